// Round 5
// baseline (107.233 us; speedup 1.0000x reference)
//
#include <hip/hip_runtime.h>
#include <hip/hip_fp16.h>

#define GAT_ALPHA 0.2f
#define GAT_NEG_INF -9.0e15f

typedef _Float16 half8_t __attribute__((ext_vector_type(8)));
typedef _Float16 half4_t __attribute__((ext_vector_type(4)));
typedef float f32x4 __attribute__((ext_vector_type(4)));

// k1: MFMA f16 GEMM. Wh = fp16(h @ W_j) stored as TWO dim-planes
// (dims 0-63 -> Wh0, 64-127 -> Wh1; 2.56 MB each so one plane fits a
// 4 MB XCD L2 during the gather passes). e2 = Wh@a_j (fp32 acc);
// e1 = h@vi + ab. One wave = one 16-node tile. (Round-0 structure.)
__global__ __launch_bounds__(256) void gat_transform_mfma(
    const float* __restrict__ h, const float* __restrict__ Wi,
    const float* __restrict__ Wj, const float* __restrict__ aw,
    const float* __restrict__ ab,
    __half* __restrict__ Wh0, __half* __restrict__ Wh1,
    float* __restrict__ e1, float* __restrict__ e2, int N) {
    __shared__ _Float16 sWt[128 * 136];  // W_j^T, padded: 34816 B
    __shared__ float svi[128];           // vi = W_i @ a_i
    const int t = threadIdx.x;

    // prologue 1: vi (threads 0..127)
    if (t < 128) {
        const float4* wrow = (const float4*)(Wi + (size_t)t * 128);
        const float4* a4 = (const float4*)aw;  // a_i = aw[0:128]
        float s = 0.f;
        #pragma unroll
        for (int i = 0; i < 32; ++i) {
            float4 w = wrow[i], a = a4[i];
            s = fmaf(w.x, a.x, s); s = fmaf(w.y, a.y, s);
            s = fmaf(w.z, a.z, s); s = fmaf(w.w, a.w, s);
        }
        svi[t] = s;
    }
    // prologue 2: W_j^T into LDS as fp16
    for (int i = t; i < 128 * 128; i += 256) {
        int k = i >> 7, n = i & 127;          // W_j[k][n] row-major read
        sWt[n * 136 + k] = (_Float16)Wj[i];
    }
    __syncthreads();

    const int wave = t >> 6, lane = t & 63, q = lane >> 4, l16 = lane & 15;
    const float abv = ab[0];

    float vir[4][8];
    #pragma unroll
    for (int s = 0; s < 4; ++s) {
        float4 u0 = *(const float4*)(svi + s * 32 + q * 8);
        float4 u1 = *(const float4*)(svi + s * 32 + q * 8 + 4);
        vir[s][0] = u0.x; vir[s][1] = u0.y; vir[s][2] = u0.z; vir[s][3] = u0.w;
        vir[s][4] = u1.x; vir[s][5] = u1.y; vir[s][6] = u1.z; vir[s][7] = u1.w;
    }
    float ajr[8];
    #pragma unroll
    for (int c = 0; c < 8; ++c) ajr[c] = aw[128 + c * 16 + l16];

    const int ntiles = (N + 15) >> 4;
    for (int tile = blockIdx.x * 4 + wave; tile < ntiles; tile += gridDim.x * 4) {
        const int base = tile << 4;
        int row = base + l16; if (row >= N) row = N - 1;  // clamp tail
        const float* hp = h + (size_t)row * 128 + q * 8;

        half8_t af[4];
        float pe1 = 0.f;
        #pragma unroll
        for (int s = 0; s < 4; ++s) {
            float4 f0 = *(const float4*)(hp + s * 32);
            float4 f1 = *(const float4*)(hp + s * 32 + 4);
            pe1 = fmaf(f0.x, vir[s][0], pe1); pe1 = fmaf(f0.y, vir[s][1], pe1);
            pe1 = fmaf(f0.z, vir[s][2], pe1); pe1 = fmaf(f0.w, vir[s][3], pe1);
            pe1 = fmaf(f1.x, vir[s][4], pe1); pe1 = fmaf(f1.y, vir[s][5], pe1);
            pe1 = fmaf(f1.z, vir[s][6], pe1); pe1 = fmaf(f1.w, vir[s][7], pe1);
            half8_t a;
            a[0] = (_Float16)f0.x; a[1] = (_Float16)f0.y;
            a[2] = (_Float16)f0.z; a[3] = (_Float16)f0.w;
            a[4] = (_Float16)f1.x; a[5] = (_Float16)f1.y;
            a[6] = (_Float16)f1.z; a[7] = (_Float16)f1.w;
            af[s] = a;
        }

        f32x4 acc[8];
        #pragma unroll
        for (int c = 0; c < 8; ++c) { f32x4 z = {0.f, 0.f, 0.f, 0.f}; acc[c] = z; }

        const _Float16* wbase = sWt + l16 * 136 + q * 8;
        #pragma unroll
        for (int s = 0; s < 4; ++s) {
            #pragma unroll
            for (int c = 0; c < 8; ++c) {
                half8_t bf = *(const half8_t*)(wbase + c * (16 * 136) + s * 32);
                acc[c] = __builtin_amdgcn_mfma_f32_16x16x32_f16(af[s], bf, acc[c], 0, 0, 0);
            }
        }

        // Epilogue. D layout: col = c*16 + l16, row(node) = base + q*4 + r.
        // Plane select is compile-time (c<4 -> plane 0). Same 32B-chunk
        // store coalescing as the interleaved layout.
        const bool full = (base + 16 <= N);
        float pe2[4] = {0.f, 0.f, 0.f, 0.f};
        #pragma unroll
        for (int c = 0; c < 8; ++c) {
            __half* dst = (c < 4) ? Wh0 : Wh1;
            const int c64 = (c & 3) * 16 + l16;
            #pragma unroll
            for (int r = 0; r < 4; ++r) {
                float v = acc[c][r];
                pe2[r] = fmaf(v, ajr[c], pe2[r]);
                int rr = base + q * 4 + r;
                if (full || rr < N)
                    dst[(size_t)rr * 64 + c64] = __float2half(v);
            }
        }
        #pragma unroll
        for (int r = 0; r < 4; ++r) {
            pe2[r] += __shfl_xor(pe2[r], 1);
            pe2[r] += __shfl_xor(pe2[r], 2);
            pe2[r] += __shfl_xor(pe2[r], 4);
            pe2[r] += __shfl_xor(pe2[r], 8);
        }
        if (l16 == 0) {
            #pragma unroll
            for (int r = 0; r < 4; ++r) {
                int rr = base + q * 4 + r;
                if (rr < N) e2[rr] = pe2[r];
            }
        }
        pe1 += __shfl_xor(pe1, 16);
        pe1 += __shfl_xor(pe1, 32);
        if (lane < 16) {
            int rr = base + lane;
            if (rr < N) e1[rr] = pe1 + abv;
        }
    }
}

// k2: one 64-dim PLANE per launch (table slice 2.56 MB -> fits every
// XCD's private 4 MB L2; the 5.12 MB interleaved table thrashed it).
// 1 node/wave; quarter q owns neighbors 8q..8q+7; lane owns 8 B (4 dims).
// ctx loads and out stores are NONTEMPORAL so streaming traffic doesn't
// evict table lines. Softmax recomputed per pass (shuffle/VALU, cheap).
__global__ __launch_bounds__(256, 8) void gat_gather_plane(
    const int* __restrict__ ctx, const float* __restrict__ e1,
    const float* __restrict__ e2, const __half* __restrict__ plane,
    float* __restrict__ out, int N, int dbase) {
    const int t = threadIdx.x;
    const int wave = t >> 6, lane = t & 63;
    const int qq = lane >> 4, ll = lane & 15;
    const int n = blockIdx.x * 4 + wave;
    if (n >= N) return;  // wave-uniform exit

    // (1) neighbor index (lane&31; upper half mirrors), streamed past L2
    const int c32 = lane & 31;
    const int j = __builtin_nontemporal_load(ctx + (size_t)n * 32 + c32);
    const bool v = (j >= 0);
    const int jj = v ? j : 0;
    const float eb = e1[n];

    // (2) e2 gather (gates softmax; 80 KB table, L2-resident)
    const float e2v = e2[jj];

    // (3) issue this quarter's 8 plane-row gathers before softmax
    const int o = jj << 7;               // 128 B plane rows
    const int qb = qq * 8;
    const char* wb = (const char*)plane + (size_t)(ll * 8);
    const int off0 = __shfl(o, qb + 0, 32);
    const int off1 = __shfl(o, qb + 1, 32);
    const int off2 = __shfl(o, qb + 2, 32);
    const int off3 = __shfl(o, qb + 3, 32);
    const int off4 = __shfl(o, qb + 4, 32);
    const int off5 = __shfl(o, qb + 5, 32);
    const int off6 = __shfl(o, qb + 6, 32);
    const int off7 = __shfl(o, qb + 7, 32);
    half4_t hv0 = *(const half4_t*)(wb + off0);
    half4_t hv1 = *(const half4_t*)(wb + off1);
    half4_t hv2 = *(const half4_t*)(wb + off2);
    half4_t hv3 = *(const half4_t*)(wb + off3);
    half4_t hv4 = *(const half4_t*)(wb + off4);
    half4_t hv5 = *(const half4_t*)(wb + off5);
    half4_t hv6 = *(const half4_t*)(wb + off6);
    half4_t hv7 = *(const half4_t*)(wb + off7);

    // (4) softmax over the 32 neighbors (width-32 shuffles)
    float lg = eb + e2v;
    lg = fmaxf(lg, GAT_ALPHA * lg);      // leaky_relu (alpha<1)
    lg = v ? lg : GAT_NEG_INF;
    float m = lg;
    #pragma unroll
    for (int s = 16; s; s >>= 1) m = fmaxf(m, __shfl_xor(m, s, 32));
    float p = v ? __expf(lg - m) : 0.f;
    float ss = p;
    #pragma unroll
    for (int s = 16; s; s >>= 1) ss += __shfl_xor(ss, s, 32);
    const float inv = (ss > 0.f) ? __frcp_rn(ss) : 0.f;
    p *= inv;

    // (5) weights for this quarter's 8 rows
    const float w0 = __shfl(p, qb + 0, 32);
    const float w1 = __shfl(p, qb + 1, 32);
    const float w2 = __shfl(p, qb + 2, 32);
    const float w3 = __shfl(p, qb + 3, 32);
    const float w4 = __shfl(p, qb + 4, 32);
    const float w5 = __shfl(p, qb + 5, 32);
    const float w6 = __shfl(p, qb + 6, 32);
    const float w7 = __shfl(p, qb + 7, 32);

    // (6) weighted accumulate over 4 dims
    float a0 = 0.f, a1 = 0.f, a2 = 0.f, a3 = 0.f;
#define GAT_ACC(HV, W)                                                   \
    a0 = fmaf(W, (float)HV[0], a0); a1 = fmaf(W, (float)HV[1], a1);      \
    a2 = fmaf(W, (float)HV[2], a2); a3 = fmaf(W, (float)HV[3], a3);
    GAT_ACC(hv0, w0) GAT_ACC(hv1, w1) GAT_ACC(hv2, w2) GAT_ACC(hv3, w3)
    GAT_ACC(hv4, w4) GAT_ACC(hv5, w5) GAT_ACC(hv6, w6) GAT_ACC(hv7, w7)
#undef GAT_ACC

    // (7) cross-quarter reduction (disjoint neighbor subsets, same dims)
    a0 += __shfl_xor(a0, 16); a1 += __shfl_xor(a1, 16);
    a2 += __shfl_xor(a2, 16); a3 += __shfl_xor(a3, 16);
    a0 += __shfl_xor(a0, 32); a1 += __shfl_xor(a1, 32);
    a2 += __shfl_xor(a2, 32); a3 += __shfl_xor(a3, 32);

    if (lane < 16) {  // 16 lanes x 16 B = 256 B contiguous half-row
        f32x4 u; u[0] = a0; u[1] = a1; u[2] = a2; u[3] = a3;
        f32x4* orow = (f32x4*)(out + (size_t)n * 128 + dbase) + ll;
        __builtin_nontemporal_store(u, orow);
    }
}

extern "C" void kernel_launch(void* const* d_in, const int* in_sizes, int n_in,
                              void* d_out, int out_size, void* d_ws, size_t ws_size,
                              hipStream_t stream) {
    const float* h   = (const float*)d_in[0];
    const int*   ctx = (const int*)d_in[1];
    const float* Wi  = (const float*)d_in[2];
    const float* Wj  = (const float*)d_in[3];
    const float* aw  = (const float*)d_in[4];
    const float* ab  = (const float*)d_in[5];
    float* out = (float*)d_out;
    const int N = in_sizes[0] / 128;

    // workspace: e1[N] | e2[N] | Wh0[N*64] fp16 | Wh1[N*64] fp16
    float* e1 = (float*)d_ws;
    float* e2 = e1 + N;
    __half* Wh0 = (__half*)(e2 + N);
    __half* Wh1 = Wh0 + (size_t)N * 64;

    const int ntiles = (N + 15) >> 4;       // 16-node MFMA tiles
    const int g1 = (ntiles + 3) / 4;        // 4 waves/block, 1 tile/wave
    const int g2 = (N + 3) / 4;             // 1 node/wave, 4 waves/block

    gat_transform_mfma<<<g1, 256, 0, stream>>>(h, Wi, Wj, aw, ab, Wh0, Wh1, e1, e2, N);
    gat_gather_plane<<<g2, 256, 0, stream>>>(ctx, e1, e2, Wh0, out, N, 0);
    gat_gather_plane<<<g2, 256, 0, stream>>>(ctx, e1, e2, Wh1, out, N, 64);
}

// Round 6
// 105.534 us; speedup vs baseline: 1.0161x; 1.0161x over previous
//
#include <hip/hip_runtime.h>
#include <hip/hip_fp16.h>

#define GAT_ALPHA 0.2f
#define GAT_NEG_INF -9.0e15f

typedef _Float16 half8_t __attribute__((ext_vector_type(8)));
typedef float f32x4 __attribute__((ext_vector_type(4)));

// k1: MFMA f16 GEMM. Wh16 = fp16(h @ W_j) (interleaved 256 B rows);
// e1 = h@vi + ab (vi = W_i@a_i from the prologue). e2 is NO LONGER
// materialized: k2 recomputes it from the gathered Wh16 rows (saves the
// 32-line/wave random e2 gather that was ~1/3 of k2's line-requests).
__global__ __launch_bounds__(256) void gat_transform_mfma(
    const float* __restrict__ h, const float* __restrict__ Wi,
    const float* __restrict__ Wj, const float* __restrict__ aw,
    const float* __restrict__ ab,
    __half* __restrict__ Wh16, float* __restrict__ e1, int N) {
    __shared__ _Float16 sWt[128 * 136];  // W_j^T, padded: 34816 B
    __shared__ float svi[128];           // vi = W_i @ a_i
    const int t = threadIdx.x;

    // prologue 1: vi (threads 0..127)
    if (t < 128) {
        const float4* wrow = (const float4*)(Wi + (size_t)t * 128);
        const float4* a4 = (const float4*)aw;  // a_i = aw[0:128]
        float s = 0.f;
        #pragma unroll
        for (int i = 0; i < 32; ++i) {
            float4 w = wrow[i], a = a4[i];
            s = fmaf(w.x, a.x, s); s = fmaf(w.y, a.y, s);
            s = fmaf(w.z, a.z, s); s = fmaf(w.w, a.w, s);
        }
        svi[t] = s;
    }
    // prologue 2: W_j^T into LDS as fp16
    for (int i = t; i < 128 * 128; i += 256) {
        int k = i >> 7, n = i & 127;          // W_j[k][n] row-major read
        sWt[n * 136 + k] = (_Float16)Wj[i];
    }
    __syncthreads();

    const int wave = t >> 6, lane = t & 63, q = lane >> 4, l16 = lane & 15;
    const float abv = ab[0];

    // vi chunk this lane consumes for e1: vi[s*32 + q*8 + j]
    float vir[4][8];
    #pragma unroll
    for (int s = 0; s < 4; ++s) {
        float4 u0 = *(const float4*)(svi + s * 32 + q * 8);
        float4 u1 = *(const float4*)(svi + s * 32 + q * 8 + 4);
        vir[s][0] = u0.x; vir[s][1] = u0.y; vir[s][2] = u0.z; vir[s][3] = u0.w;
        vir[s][4] = u1.x; vir[s][5] = u1.y; vir[s][6] = u1.z; vir[s][7] = u1.w;
    }

    const int ntiles = (N + 15) >> 4;
    for (int tile = blockIdx.x * 4 + wave; tile < ntiles; tile += gridDim.x * 4) {
        const int base = tile << 4;
        int row = base + l16; if (row >= N) row = N - 1;  // clamp tail
        const float* hp = h + (size_t)row * 128 + q * 8;

        half8_t af[4];
        float pe1 = 0.f;  // fp32-exact partial of h[row]·vi
        #pragma unroll
        for (int s = 0; s < 4; ++s) {
            float4 f0 = *(const float4*)(hp + s * 32);
            float4 f1 = *(const float4*)(hp + s * 32 + 4);
            pe1 = fmaf(f0.x, vir[s][0], pe1); pe1 = fmaf(f0.y, vir[s][1], pe1);
            pe1 = fmaf(f0.z, vir[s][2], pe1); pe1 = fmaf(f0.w, vir[s][3], pe1);
            pe1 = fmaf(f1.x, vir[s][4], pe1); pe1 = fmaf(f1.y, vir[s][5], pe1);
            pe1 = fmaf(f1.z, vir[s][6], pe1); pe1 = fmaf(f1.w, vir[s][7], pe1);
            half8_t a;
            a[0] = (_Float16)f0.x; a[1] = (_Float16)f0.y;
            a[2] = (_Float16)f0.z; a[3] = (_Float16)f0.w;
            a[4] = (_Float16)f1.x; a[5] = (_Float16)f1.y;
            a[6] = (_Float16)f1.z; a[7] = (_Float16)f1.w;
            af[s] = a;
        }

        f32x4 acc[8];
        #pragma unroll
        for (int c = 0; c < 8; ++c) { f32x4 z = {0.f, 0.f, 0.f, 0.f}; acc[c] = z; }

        const _Float16* wbase = sWt + l16 * 136 + q * 8;
        #pragma unroll
        for (int s = 0; s < 4; ++s) {
            #pragma unroll
            for (int c = 0; c < 8; ++c) {
                half8_t bf = *(const half8_t*)(wbase + c * (16 * 136) + s * 32);
                acc[c] = __builtin_amdgcn_mfma_f32_16x16x32_f16(af[s], bf, acc[c], 0, 0, 0);
            }
        }

        // Epilogue. D layout: col = c*16 + l16, row(node) = base + q*4 + r.
        const bool full = (base + 16 <= N);
        #pragma unroll
        for (int c = 0; c < 8; ++c) {
            #pragma unroll
            for (int r = 0; r < 4; ++r) {
                int rr = base + q * 4 + r;
                if (full || rr < N)
                    Wh16[(size_t)rr * 128 + (c * 16 + l16)] = __float2half(acc[c][r]);
            }
        }
        pe1 += __shfl_xor(pe1, 16);  // reduce over q (k-chunks)
        pe1 += __shfl_xor(pe1, 32);
        if (lane < 16) {
            int rr = base + lane;
            if (rr < N) e1[rr] = pe1 + abv;
        }
    }
}

// k2: 1 node/wave. The ONLY random gather is the 8 Wh16 rows per quarter
// (64 lines/wave). e2[j] is recomputed from the gathered rows in-register
// (8-dim partial dot + 16-lane butterfly per row), eliminating the
// separate 32-line e2 gather. Quarter q owns neighbors 8q..8q+7 and holds
// their weights locally (no weight redistribution shuffles).
__global__ __launch_bounds__(256, 4) void gat_gather_fused(
    const int* __restrict__ ctx, const float* __restrict__ e1,
    const float* __restrict__ aw, const __half* __restrict__ Wh16,
    float* __restrict__ out, int N) {
    const int t = threadIdx.x;
    const int wave = t >> 6, lane = t & 63;
    const int qq = lane >> 4, ll = lane & 15;
    const int n = blockIdx.x * 4 + wave;
    if (n >= N) return;  // wave-uniform exit

    // (1) neighbor index: lane c32 owns neighbor c32 (upper half mirrors)
    const int c32 = lane & 31;
    const int j = __builtin_nontemporal_load(ctx + (size_t)n * 32 + c32);
    const float eb = e1[n];  // includes a_b

    // (2) distribute this quarter's 8 neighbor indices
    const int qb = qq * 8;
    const int j0 = __shfl(j, qb + 0, 32);
    const int j1 = __shfl(j, qb + 1, 32);
    const int j2 = __shfl(j, qb + 2, 32);
    const int j3 = __shfl(j, qb + 3, 32);
    const int j4 = __shfl(j, qb + 4, 32);
    const int j5 = __shfl(j, qb + 5, 32);
    const int j6 = __shfl(j, qb + 6, 32);
    const int j7 = __shfl(j, qb + 7, 32);
    const bool v0 = j0 >= 0, v1 = j1 >= 0, v2 = j2 >= 0, v3 = j3 >= 0;
    const bool v4 = j4 >= 0, v5 = j5 >= 0, v6 = j6 >= 0, v7 = j7 >= 0;

    // (3) gather the 8 rows — the only random gather in the kernel
    const char* wb = (const char*)Wh16 + (size_t)(ll * 16);
    half8_t hv0 = *(const half8_t*)(wb + ((v0 ? j0 : 0) << 8));
    half8_t hv1 = *(const half8_t*)(wb + ((v1 ? j1 : 0) << 8));
    half8_t hv2 = *(const half8_t*)(wb + ((v2 ? j2 : 0) << 8));
    half8_t hv3 = *(const half8_t*)(wb + ((v3 ? j3 : 0) << 8));
    half8_t hv4 = *(const half8_t*)(wb + ((v4 ? j4 : 0) << 8));
    half8_t hv5 = *(const half8_t*)(wb + ((v5 ? j5 : 0) << 8));
    half8_t hv6 = *(const half8_t*)(wb + ((v6 ? j6 : 0) << 8));
    half8_t hv7 = *(const half8_t*)(wb + ((v7 ? j7 : 0) << 8));

    // (4) a_j chunk for this lane's 8 dims (dims ll*8 .. ll*8+7)
    const float4 aj0 = *(const float4*)(aw + 128 + ll * 8);
    const float4 aj1 = *(const float4*)(aw + 128 + ll * 8 + 4);

    // (5) e2 per row: partial dot over this lane's 8 dims, then 16-lane
    //     butterfly -> every lane of the quarter holds the full dot
#define GAT_DOT(HV, D)                                                     \
    float D = fmaf((float)HV[0], aj0.x, 0.f);                              \
    D = fmaf((float)HV[1], aj0.y, D); D = fmaf((float)HV[2], aj0.z, D);    \
    D = fmaf((float)HV[3], aj0.w, D); D = fmaf((float)HV[4], aj1.x, D);    \
    D = fmaf((float)HV[5], aj1.y, D); D = fmaf((float)HV[6], aj1.z, D);    \
    D = fmaf((float)HV[7], aj1.w, D);                                      \
    D += __shfl_xor(D, 1, 16); D += __shfl_xor(D, 2, 16);                  \
    D += __shfl_xor(D, 4, 16); D += __shfl_xor(D, 8, 16);
    GAT_DOT(hv0, d0) GAT_DOT(hv1, d1) GAT_DOT(hv2, d2) GAT_DOT(hv3, d3)
    GAT_DOT(hv4, d4) GAT_DOT(hv5, d5) GAT_DOT(hv6, d6) GAT_DOT(hv7, d7)
#undef GAT_DOT

    // (6) logits: e1[n] + e2[j], leaky_relu, validity mask
#define GAT_LG(D, V)                                                       \
    D = eb + D; D = fmaxf(D, GAT_ALPHA * D); D = V ? D : GAT_NEG_INF;
    GAT_LG(d0, v0) GAT_LG(d1, v1) GAT_LG(d2, v2) GAT_LG(d3, v3)
    GAT_LG(d4, v4) GAT_LG(d5, v5) GAT_LG(d6, v6) GAT_LG(d7, v7)
#undef GAT_LG

    // (7) softmax over 32 neighbors: local-8 then cross-quarter butterfly
    float m = fmaxf(fmaxf(fmaxf(d0, d1), fmaxf(d2, d3)),
                    fmaxf(fmaxf(d4, d5), fmaxf(d6, d7)));
    m = fmaxf(m, __shfl_xor(m, 16));
    m = fmaxf(m, __shfl_xor(m, 32));
    const float p0 = v0 ? __expf(d0 - m) : 0.f;
    const float p1 = v1 ? __expf(d1 - m) : 0.f;
    const float p2 = v2 ? __expf(d2 - m) : 0.f;
    const float p3 = v3 ? __expf(d3 - m) : 0.f;
    const float p4 = v4 ? __expf(d4 - m) : 0.f;
    const float p5 = v5 ? __expf(d5 - m) : 0.f;
    const float p6 = v6 ? __expf(d6 - m) : 0.f;
    const float p7 = v7 ? __expf(d7 - m) : 0.f;
    float ss = ((p0 + p1) + (p2 + p3)) + ((p4 + p5) + (p6 + p7));
    ss += __shfl_xor(ss, 16);
    ss += __shfl_xor(ss, 32);
    const float inv = (ss > 0.f) ? __frcp_rn(ss) : 0.f;

    // (8) weighted accumulate, reusing the gathered rows (un-normalized;
    //     normalization folded into the store)
    float a0 = 0.f, a1 = 0.f, a2 = 0.f, a3 = 0.f;
    float a4 = 0.f, a5 = 0.f, a6 = 0.f, a7 = 0.f;
#define GAT_ACC(HV, W)                                                     \
    a0 = fmaf(W, (float)HV[0], a0); a1 = fmaf(W, (float)HV[1], a1);        \
    a2 = fmaf(W, (float)HV[2], a2); a3 = fmaf(W, (float)HV[3], a3);        \
    a4 = fmaf(W, (float)HV[4], a4); a5 = fmaf(W, (float)HV[5], a5);        \
    a6 = fmaf(W, (float)HV[6], a6); a7 = fmaf(W, (float)HV[7], a7);
    GAT_ACC(hv0, p0) GAT_ACC(hv1, p1) GAT_ACC(hv2, p2) GAT_ACC(hv3, p3)
    GAT_ACC(hv4, p4) GAT_ACC(hv5, p5) GAT_ACC(hv6, p6) GAT_ACC(hv7, p7)
#undef GAT_ACC

    // (9) cross-quarter reduction (disjoint neighbor subsets, same dims)
    a0 += __shfl_xor(a0, 16); a1 += __shfl_xor(a1, 16);
    a2 += __shfl_xor(a2, 16); a3 += __shfl_xor(a3, 16);
    a4 += __shfl_xor(a4, 16); a5 += __shfl_xor(a5, 16);
    a6 += __shfl_xor(a6, 16); a7 += __shfl_xor(a7, 16);
    a0 += __shfl_xor(a0, 32); a1 += __shfl_xor(a1, 32);
    a2 += __shfl_xor(a2, 32); a3 += __shfl_xor(a3, 32);
    a4 += __shfl_xor(a4, 32); a5 += __shfl_xor(a5, 32);
    a6 += __shfl_xor(a6, 32); a7 += __shfl_xor(a7, 32);

    if (lane < 16) {  // 16 lanes x 32 B contiguous = 512 B row
        f32x4 u; u[0] = a0 * inv; u[1] = a1 * inv;
        u[2] = a2 * inv; u[3] = a3 * inv;
        f32x4 w2; w2[0] = a4 * inv; w2[1] = a5 * inv;
        w2[2] = a6 * inv; w2[3] = a7 * inv;
        f32x4* orow = (f32x4*)(out + (size_t)n * 128) + 2 * ll;
        __builtin_nontemporal_store(u, orow);
        __builtin_nontemporal_store(w2, orow + 1);
    }
}

extern "C" void kernel_launch(void* const* d_in, const int* in_sizes, int n_in,
                              void* d_out, int out_size, void* d_ws, size_t ws_size,
                              hipStream_t stream) {
    const float* h   = (const float*)d_in[0];
    const int*   ctx = (const int*)d_in[1];
    const float* Wi  = (const float*)d_in[2];
    const float* Wj  = (const float*)d_in[3];
    const float* aw  = (const float*)d_in[4];
    const float* ab  = (const float*)d_in[5];
    float* out = (float*)d_out;
    const int N = in_sizes[0] / 128;

    // workspace: e1[Npad] | Wh16[N*128] fp16   (no e2 buffer anymore)
    const int Npad = (N + 7) & ~7;
    float* e1 = (float*)d_ws;
    __half* Wh16 = (__half*)(e1 + Npad);

    const int ntiles = (N + 15) >> 4;       // 16-node MFMA tiles
    const int g1 = (ntiles + 3) / 4;        // 4 waves/block, 1 tile/wave
    const int g2 = (N + 3) / 4;             // 1 node/wave, 4 waves/block

    gat_transform_mfma<<<g1, 256, 0, stream>>>(h, Wi, Wj, aw, ab, Wh16, e1, N);
    gat_gather_fused<<<g2, 256, 0, stream>>>(ctx, e1, aw, Wh16, out, N);
}

// Round 7
// 99.889 us; speedup vs baseline: 1.0735x; 1.0565x over previous
//
#include <hip/hip_runtime.h>
#include <hip/hip_fp16.h>

#define GAT_ALPHA 0.2f
#define GAT_NEG_INF -9.0e15f

typedef _Float16 half8_t __attribute__((ext_vector_type(8)));
typedef float f32x4 __attribute__((ext_vector_type(4)));

// k0: one-time weight prep (was a per-block prologue in k1 — 313x redundant).
// WjT16[n][k] = fp16(Wj[k][n]); vi = W_i @ a_i. 16 blocks, ~130 KB of reads.
__global__ __launch_bounds__(256) void gat_prep(
    const float* __restrict__ Wi, const float* __restrict__ Wj,
    const float* __restrict__ aw, __half* __restrict__ WjT16,
    float* __restrict__ vi) {
    const int gid = blockIdx.x * 256 + threadIdx.x;  // 16 blocks x 256
    const int k = gid >> 5, n0 = (gid & 31) * 4;
    if (k < 128) {
        // coalesced float4 read of Wj row k; scattered 2B writes (L2-absorbed)
        float4 w = *(const float4*)(Wj + (size_t)k * 128 + n0);
        WjT16[(size_t)(n0 + 0) * 128 + k] = __float2half(w.x);
        WjT16[(size_t)(n0 + 1) * 128 + k] = __float2half(w.y);
        WjT16[(size_t)(n0 + 2) * 128 + k] = __float2half(w.z);
        WjT16[(size_t)(n0 + 3) * 128 + k] = __float2half(w.w);
    }
    if (blockIdx.x == 0 && threadIdx.x < 128) {
        const float4* wrow = (const float4*)(Wi + (size_t)threadIdx.x * 128);
        const float4* a4 = (const float4*)aw;  // a_i = aw[0:128]
        float s = 0.f;
        #pragma unroll
        for (int i = 0; i < 32; ++i) {
            float4 w = wrow[i], a = a4[i];
            s = fmaf(w.x, a.x, s); s = fmaf(w.y, a.y, s);
            s = fmaf(w.z, a.z, s); s = fmaf(w.w, a.w, s);
        }
        vi[threadIdx.x] = s;
    }
}

// k1: MFMA f16 GEMM. Wh16 = fp16(h @ W_j); e2 = Wh@a_j; e1 = h@vi + ab.
// Prologue is now a vectorized 32 KB copy (WjT16 global -> LDS, 8x dwordx4
// + 8x ds_write_b128 per thread) instead of 128 KB fp32 reads + 16K scalar
// converts + strided 2B LDS writes. vi read directly from L2-hot global.
__global__ __launch_bounds__(256) void gat_transform_mfma(
    const float* __restrict__ h, const float* __restrict__ aw,
    const float* __restrict__ ab, const __half* __restrict__ WjT16,
    const float* __restrict__ vi,
    __half* __restrict__ Wh16, float* __restrict__ e1, float* __restrict__ e2,
    int N) {
    __shared__ _Float16 sWt[128 * 136];  // W_j^T, padded row stride 136
    const int t = threadIdx.x;

    // prologue: 2048 16B-chunks / 256 threads = 8 per thread, coalesced
    for (int c = t; c < 2048; c += 256) {
        const int n = c >> 4, seg = c & 15;
        *(half8_t*)(sWt + n * 136 + seg * 8) =
            *(const half8_t*)((const _Float16*)WjT16 + n * 128 + seg * 8);
    }
    __syncthreads();

    const int wave = t >> 6, lane = t & 63, q = lane >> 4, l16 = lane & 15;
    const float abv = ab[0];

    // vi chunk this lane consumes for e1 (global, L2-hot broadcast)
    float vir[4][8];
    #pragma unroll
    for (int s = 0; s < 4; ++s) {
        float4 u0 = *(const float4*)(vi + s * 32 + q * 8);
        float4 u1 = *(const float4*)(vi + s * 32 + q * 8 + 4);
        vir[s][0] = u0.x; vir[s][1] = u0.y; vir[s][2] = u0.z; vir[s][3] = u0.w;
        vir[s][4] = u1.x; vir[s][5] = u1.y; vir[s][6] = u1.z; vir[s][7] = u1.w;
    }
    // a_j value for this lane's output column in each of the 8 col-tiles
    float ajr[8];
    #pragma unroll
    for (int c = 0; c < 8; ++c) ajr[c] = aw[128 + c * 16 + l16];

    const int ntiles = (N + 15) >> 4;
    for (int tile = blockIdx.x * 4 + wave; tile < ntiles; tile += gridDim.x * 4) {
        const int base = tile << 4;
        int row = base + l16; if (row >= N) row = N - 1;  // clamp tail
        const float* hp = h + (size_t)row * 128 + q * 8;

        half8_t af[4];
        float pe1 = 0.f;  // fp32-exact partial of h[row]·vi
        #pragma unroll
        for (int s = 0; s < 4; ++s) {
            float4 f0 = *(const float4*)(hp + s * 32);
            float4 f1 = *(const float4*)(hp + s * 32 + 4);
            pe1 = fmaf(f0.x, vir[s][0], pe1); pe1 = fmaf(f0.y, vir[s][1], pe1);
            pe1 = fmaf(f0.z, vir[s][2], pe1); pe1 = fmaf(f0.w, vir[s][3], pe1);
            pe1 = fmaf(f1.x, vir[s][4], pe1); pe1 = fmaf(f1.y, vir[s][5], pe1);
            pe1 = fmaf(f1.z, vir[s][6], pe1); pe1 = fmaf(f1.w, vir[s][7], pe1);
            half8_t a;
            a[0] = (_Float16)f0.x; a[1] = (_Float16)f0.y;
            a[2] = (_Float16)f0.z; a[3] = (_Float16)f0.w;
            a[4] = (_Float16)f1.x; a[5] = (_Float16)f1.y;
            a[6] = (_Float16)f1.z; a[7] = (_Float16)f1.w;
            af[s] = a;
        }

        f32x4 acc[8];
        #pragma unroll
        for (int c = 0; c < 8; ++c) { f32x4 z = {0.f, 0.f, 0.f, 0.f}; acc[c] = z; }

        const _Float16* wbase = sWt + l16 * 136 + q * 8;
        #pragma unroll
        for (int s = 0; s < 4; ++s) {
            #pragma unroll
            for (int c = 0; c < 8; ++c) {
                half8_t bf = *(const half8_t*)(wbase + c * (16 * 136) + s * 32);
                acc[c] = __builtin_amdgcn_mfma_f32_16x16x32_f16(af[s], bf, acc[c], 0, 0, 0);
            }
        }

        // Epilogue. D layout: col = c*16 + l16, row(node) = base + q*4 + r.
        const bool full = (base + 16 <= N);
        float pe2[4] = {0.f, 0.f, 0.f, 0.f};
        #pragma unroll
        for (int c = 0; c < 8; ++c) {
            #pragma unroll
            for (int r = 0; r < 4; ++r) {
                float v = acc[c][r];
                pe2[r] = fmaf(v, ajr[c], pe2[r]);
                int rr = base + q * 4 + r;
                if (full || rr < N)
                    Wh16[(size_t)rr * 128 + (c * 16 + l16)] = __float2half(v);
            }
        }
        #pragma unroll
        for (int r = 0; r < 4; ++r) {  // reduce over the 16 cols held in-quad
            pe2[r] += __shfl_xor(pe2[r], 1);
            pe2[r] += __shfl_xor(pe2[r], 2);
            pe2[r] += __shfl_xor(pe2[r], 4);
            pe2[r] += __shfl_xor(pe2[r], 8);
        }
        if (l16 == 0) {
            #pragma unroll
            for (int r = 0; r < 4; ++r) {
                int rr = base + q * 4 + r;
                if (rr < N) e2[rr] = pe2[r];
            }
        }
        pe1 += __shfl_xor(pe1, 16);  // reduce over q (k-chunks)
        pe1 += __shfl_xor(pe1, 32);
        if (lane < 16) {
            int rr = base + lane;
            if (rr < N) e1[rr] = pe1 + abv;
        }
    }
}

// k2: EXACT round-0 gat_gather4 (best measured total). 4 nodes per wave,
// lane owns 2 neighbors (int2) + 8 output dims; quarter-local softmax.
__global__ __launch_bounds__(256) void gat_gather4(
    const int* __restrict__ ctx, const float* __restrict__ e1,
    const float* __restrict__ e2, const __half* __restrict__ Wh16,
    float* __restrict__ out, int N) {
    const int t = threadIdx.x;
    const int wave = t >> 6, lane = t & 63, qid = lane >> 4, l = lane & 15;
    const int widx = blockIdx.x * 4 + wave;
    if (widx * 4 >= N) return;  // wave-uniform exit
    const int n = widx * 4 + qid;
    const bool okn = (n < N);
    const int nn = okn ? n : (N - 1);

    int2 ij = ((const int2*)(ctx + (size_t)nn * 32))[l];  // neighbors 2l,2l+1
    const bool v0 = (ij.x >= 0), v1 = (ij.y >= 0);
    const int j0 = v0 ? ij.x : 0, j1 = v1 ? ij.y : 0;
    const float eb = e1[nn];  // includes a_b
    float lg0 = eb + e2[j0], lg1 = eb + e2[j1];
    lg0 = fmaxf(lg0, GAT_ALPHA * lg0);  // leaky_relu (alpha<1)
    lg1 = fmaxf(lg1, GAT_ALPHA * lg1);
    lg0 = v0 ? lg0 : GAT_NEG_INF;
    lg1 = v1 ? lg1 : GAT_NEG_INF;
    float m = fmaxf(lg0, lg1);
    #pragma unroll
    for (int s = 8; s; s >>= 1) m = fmaxf(m, __shfl_xor(m, s, 16));
    float p0 = v0 ? __expf(lg0 - m) : 0.f;
    float p1 = v1 ? __expf(lg1 - m) : 0.f;
    float ss = p0 + p1;
    #pragma unroll
    for (int s = 8; s; s >>= 1) ss += __shfl_xor(ss, s, 16);
    const float inv = (ss > 0.f) ? __frcp_rn(ss) : 0.f;
    p0 *= inv; p1 *= inv;

    const int o0 = j0 << 8, o1 = j1 << 8;  // byte offset of 256 B rows
    float a0 = 0.f, a1 = 0.f, a2 = 0.f, a3 = 0.f;
    float a4 = 0.f, a5 = 0.f, a6 = 0.f, a7 = 0.f;
    const char* wb = (const char*)Wh16 + (size_t)(l * 16);
    #pragma unroll 8
    for (int cc = 0; cc < 32; ++cc) {
        const int src = cc >> 1;
        float w   = __shfl((cc & 1) ? p1 : p0, src, 16);
        int   off = __shfl((cc & 1) ? o1 : o0, src, 16);
        half8_t hv = *(const half8_t*)(wb + off);  // 16 B, quarter = 256 B row
        a0 = fmaf(w, (float)hv[0], a0); a1 = fmaf(w, (float)hv[1], a1);
        a2 = fmaf(w, (float)hv[2], a2); a3 = fmaf(w, (float)hv[3], a3);
        a4 = fmaf(w, (float)hv[4], a4); a5 = fmaf(w, (float)hv[5], a5);
        a6 = fmaf(w, (float)hv[6], a6); a7 = fmaf(w, (float)hv[7], a7);
    }
    if (okn) {
        float4* orow = (float4*)(out + (size_t)n * 128);
        float4 u; u.x = a0; u.y = a1; u.z = a2; u.w = a3;
        float4 v; v.x = a4; v.y = a5; v.z = a6; v.w = a7;
        orow[2 * l] = u;
        orow[2 * l + 1] = v;
    }
}

extern "C" void kernel_launch(void* const* d_in, const int* in_sizes, int n_in,
                              void* d_out, int out_size, void* d_ws, size_t ws_size,
                              hipStream_t stream) {
    const float* h   = (const float*)d_in[0];
    const int*   ctx = (const int*)d_in[1];
    const float* Wi  = (const float*)d_in[2];
    const float* Wj  = (const float*)d_in[3];
    const float* aw  = (const float*)d_in[4];
    const float* ab  = (const float*)d_in[5];
    float* out = (float*)d_out;
    const int N = in_sizes[0] / 128;

    // workspace: e1[N] | e2[N] | Wh16[N*128] fp16 | WjT16[128*128] fp16 | vi[128]
    float* e1 = (float*)d_ws;
    float* e2 = e1 + N;
    __half* Wh16 = (__half*)(e2 + N);
    __half* WjT16 = Wh16 + (size_t)N * 128;
    float* vi = (float*)(WjT16 + 128 * 128);

    const int ntiles = (N + 15) >> 4;       // 16-node MFMA tiles
    const int g1 = (ntiles + 3) / 4;        // 4 waves/block, 1 tile/wave
    const int nquad = (N + 3) / 4;          // 4 nodes/wave
    const int g2 = (nquad + 3) / 4;

    gat_prep<<<16, 256, 0, stream>>>(Wi, Wj, aw, WjT16, vi);
    gat_transform_mfma<<<g1, 256, 0, stream>>>(h, aw, ab, WjT16, vi, Wh16, e1, e2, N);
    gat_gather4<<<g2, 256, 0, stream>>>(ctx, e1, e2, Wh16, out, N);
}